// Round 1
// baseline (494.248 us; speedup 1.0000x reference)
//
#include <hip/hip_runtime.h>
#include <math.h>

#define KDIM 128
#define TLEN 512
#define BATCH 16

// One block per batch element. 256 threads = 4 waves.
//   tid = h*128 + j ; j = column (state) index, h = which half of the i-sum.
// State alpha_j lives in registers of threads tid<128 (h==0).
// Per step:
//   m  = max_j a_j                          (shfl butterfly + LDS combine)
//   p_j = exp(a_j - m)  -> LDS
//   q_j = sum_i p_i * E[i][j]               (E half-column in 64 VGPRs/thread)
//   a_j = em[t,j] + m + log(q_j)
__global__ __launch_bounds__(256) void crf_forward(
    const float* __restrict__ trans,      // K*K
    const float* __restrict__ em,         // B*T*K
    const int*   __restrict__ seq_lens,   // B
    float* __restrict__ alpha_out,        // B*T*K
    float* __restrict__ logZ_out)         // B
{
    const int b   = blockIdx.x;
    const int tid = threadIdx.x;
    const int j   = tid & (KDIM - 1);
    const int h   = tid >> 7;            // 0 or 1 (wave-uniform)

    __shared__ __align__(16) float p_lds[KDIM];
    __shared__ float part[KDIM];
    __shared__ float red[8];

    // E[i][j] for i in [h*64, h*64+64) -> registers (fully unrolled -> no scratch)
    float Ereg[64];
    #pragma unroll
    for (int k = 0; k < 64; ++k) {
        Ereg[k] = __expf(trans[(h * 64 + k) * KDIM + j]);
    }

    const int len = seq_lens[b];
    const float* emb  = em        + (size_t)b * TLEN * KDIM;
    float*       outb = alpha_out + (size_t)b * TLEN * KDIM;

    float a      = 0.f;   // alpha_j (valid on h==0 threads)
    float last_a = 0.f;   // alpha at t = len-1

    if (h == 0) {
        a = emb[j];
        outb[j] = a;
        if (len == 1) last_a = a;
    }

    for (int t = 1; t < TLEN; ++t) {
        // ---- 1. m = max_j a_j ----
        {
            float v = (h == 0) ? a : -INFINITY;
            #pragma unroll
            for (int o = 32; o >= 1; o >>= 1)
                v = fmaxf(v, __shfl_xor(v, o));
            if ((tid & 63) == 0) red[tid >> 6] = v;
        }
        __syncthreads();
        const float m = fmaxf(red[0], red[1]);

        // ---- 2. p_j = exp(a_j - m) ----
        if (h == 0) p_lds[j] = __expf(a - m);
        __syncthreads();

        // prefetch emission for this step (used after matvec)
        float em_t = 0.f;
        if (h == 0) em_t = emb[t * KDIM + j];

        // ---- 3. half mat-vec: acc = sum_{k} p[h*64+k] * E[h*64+k][j] ----
        float acc0 = 0.f, acc1 = 0.f, acc2 = 0.f, acc3 = 0.f;
        const float4* p4 = (const float4*)(p_lds + h * 64);
        #pragma unroll
        for (int k4 = 0; k4 < 16; ++k4) {
            float4 pv = p4[k4];
            acc0 = fmaf(pv.x, Ereg[4 * k4 + 0], acc0);
            acc1 = fmaf(pv.y, Ereg[4 * k4 + 1], acc1);
            acc2 = fmaf(pv.z, Ereg[4 * k4 + 2], acc2);
            acc3 = fmaf(pv.w, Ereg[4 * k4 + 3], acc3);
        }
        const float acc = (acc0 + acc1) + (acc2 + acc3);

        if (h == 1) part[j] = acc;
        __syncthreads();

        // ---- 4. combine + update ----
        if (h == 0) {
            const float q = acc + part[j];
            a = em_t + m + __logf(q);
            outb[t * KDIM + j] = a;
            if (t == len - 1) last_a = a;
        }
    }

    // ---- log_Z[b] = LSE_j alpha[b, len-1, j] ----
    {
        float v = (h == 0) ? last_a : -INFINITY;
        #pragma unroll
        for (int o = 32; o >= 1; o >>= 1)
            v = fmaxf(v, __shfl_xor(v, o));
        if ((tid & 63) == 0) red[tid >> 6] = v;
    }
    __syncthreads();
    const float m2 = fmaxf(red[0], red[1]);
    float e = (h == 0) ? __expf(last_a - m2) : 0.f;
    #pragma unroll
    for (int o = 32; o >= 1; o >>= 1)
        e += __shfl_xor(e, o);
    if ((tid & 63) == 0) red[4 + (tid >> 6)] = e;
    __syncthreads();
    if (tid == 0) {
        logZ_out[b] = m2 + logf(red[4] + red[5]);
    }
}

extern "C" void kernel_launch(void* const* d_in, const int* in_sizes, int n_in,
                              void* d_out, int out_size, void* d_ws, size_t ws_size,
                              hipStream_t stream) {
    const float* trans    = (const float*)d_in[0];   // K*K
    const float* em       = (const float*)d_in[1];   // B*T*K
    const int*   seq_lens = (const int*)d_in[2];     // B

    float* alpha_out = (float*)d_out;                     // B*T*K
    float* logZ_out  = alpha_out + (size_t)BATCH * TLEN * KDIM;  // B

    crf_forward<<<BATCH, 256, 0, stream>>>(trans, em, seq_lens, alpha_out, logZ_out);
}